// Round 5
// baseline (398.584 us; speedup 1.0000x reference)
//
#include <hip/hip_runtime.h>

#define N_NODES 50000
#define DIM 256
#define NEG 0.2f
#define LN_EPS 1e-5f
#define BM_WORDS 4688           // ceil(3*50000/32) bitmap words
#define SC_BLOCKS 8

typedef __attribute__((ext_vector_type(8))) short short8;   // 8 x bf16 (4 VGPRs)
typedef __attribute__((ext_vector_type(4))) float f32x4;    // MFMA accumulator

__device__ __forceinline__ unsigned short f2bf(float x) {   // RNE fp32 -> bf16
    unsigned int u = __builtin_bit_cast(unsigned int, x);
    u += 0x7fffu + ((u >> 16) & 1u);
    return (unsigned short)(u >> 16);
}

// ---------- Wr (256x256 fp32) -> WrT bf16 [m][k] ----------
__global__ __launch_bounds__(256) void wr_to_bf16T(const float* __restrict__ Wr,
                                                   unsigned short* __restrict__ WrT) {
    __shared__ float tile[64][65];
    const int bx = (blockIdx.x & 3) * 64;    // k block
    const int by = (blockIdx.x >> 2) * 64;   // m block
    const int c = threadIdx.x & 63;
    const int r0 = threadIdx.x >> 6;
    #pragma unroll
    for (int i = 0; i < 16; ++i) {
        int r = r0 * 16 + i;
        tile[r][c] = Wr[(size_t)(bx + r) * DIM + by + c];   // coalesced read
    }
    __syncthreads();
    #pragma unroll
    for (int i = 0; i < 16; ++i) {
        int r = r0 * 16 + i;
        WrT[(size_t)(by + r) * DIM + bx + c] = f2bf(tile[c][r]);  // coalesced write
    }
}

// ---------- per-block private bitmaps: LDS atomics only, plain full-slice stores ----------
__global__ __launch_bounds__(256) void scatter_priv(
    const int* __restrict__ d0, const int* __restrict__ d1, const int* __restrict__ d2,
    int E, unsigned int* __restrict__ priv)
{
    __shared__ unsigned int lbm[BM_WORDS];
    for (int i = threadIdx.x; i < BM_WORDS; i += 256) lbm[i] = 0u;
    __syncthreads();

    const int total = 3 * E;
    const int per = (total + SC_BLOCKS - 1) / SC_BLOCKS;
    const int start = blockIdx.x * per;
    const int end = min(start + per, total);
    for (int i = start + (int)threadIdx.x; i < end; i += 256) {
        const int* d; int base, e;
        if (i >= 2 * E)  { d = d2; e = i - 2 * E; base = 2 * N_NODES; }
        else if (i >= E) { d = d1; e = i - E;     base = N_NODES; }
        else             { d = d0; e = i;         base = 0; }
        const int bit = base + d[e];
        atomicOr(&lbm[bit >> 5], 1u << (bit & 31));   // workgroup-scope LDS atomic
    }
    __syncthreads();

    unsigned int* dst = priv + (size_t)blockIdx.x * BM_WORDS;
    for (int i = threadIdx.x; i < BM_WORDS; i += 256) dst[i] = lbm[i];  // plain, every word
}

// ---------- merge 8 private maps -> byte mask (plain loads/stores, covers every byte) ----------
__global__ __launch_bounds__(256) void merge_bm(const unsigned int* __restrict__ priv,
                                                unsigned char* __restrict__ mask) {
    const int i = blockIdx.x * 256 + threadIdx.x;   // bitmap word index
    if (i >= BM_WORDS) return;
    unsigned int v = 0u;
    #pragma unroll
    for (int b = 0; b < SC_BLOCKS; ++b) v |= priv[(size_t)b * BM_WORDS + i];
    unsigned int* mw = (unsigned int*)(mask + (size_t)i * 32);   // 32-byte aligned
    #pragma unroll
    for (int j = 0; j < 8; ++j) {
        const unsigned int n = v >> (4 * j);
        mw[j] = (n & 1u) | ((n >> 1) & 1u) << 8 | ((n >> 2) & 1u) << 16 | ((n >> 3) & 1u) << 24;
    }
}

// ---------- fused MFMA GEMM + analytic-collapse epilogue (VERBATIM round-2, passed tripwire) ----------
// Each wave: 16 nodes (lane&15) x 256 out-cols (16 m-tiles). No LDS, no barriers.
__global__ __launch_bounds__(256) void fused_mfma(
    const float* __restrict__ feat, const unsigned short* __restrict__ WrT,
    const float* __restrict__ br, const float* __restrict__ rel_q,
    const float* __restrict__ rel_k, const float* __restrict__ gamma,
    const float* __restrict__ beta_p, const unsigned char* __restrict__ mask,
    float* __restrict__ out)
{
    const int lane = threadIdx.x & 63;
    const int wave = threadIdx.x >> 6;
    const int ln = lane & 15;      // node within wave / MFMA n
    const int quad = lane >> 4;    // MFMA k-quad & D-row-quad
    int node = blockIdx.x * 64 + wave * 16 + ln;
    const bool valid = node < N_NODES;
    if (!valid) node = N_NODES - 1;              // clamp: loads safe, store guarded

    f32x4 acc[16];
    #pragma unroll
    for (int mt = 0; mt < 16; ++mt) acc[mt] = (f32x4){0.f, 0.f, 0.f, 0.f};

    const float* fptr = feat + (size_t)node * DIM + quad * 8;
    const unsigned short* aptr = WrT + (size_t)ln * DIM + quad * 8;

    float4 fb0 = *(const float4*)(fptr);
    float4 fb1 = *(const float4*)(fptr + 4);

    #pragma unroll 1
    for (int k0 = 0; k0 < DIM; k0 += 32) {
        short8 bfrag;
        bfrag[0] = (short)f2bf(fb0.x); bfrag[1] = (short)f2bf(fb0.y);
        bfrag[2] = (short)f2bf(fb0.z); bfrag[3] = (short)f2bf(fb0.w);
        bfrag[4] = (short)f2bf(fb1.x); bfrag[5] = (short)f2bf(fb1.y);
        bfrag[6] = (short)f2bf(fb1.z); bfrag[7] = (short)f2bf(fb1.w);
        if (k0 + 32 < DIM) {                      // prefetch next feat chunk (HBM)
            fb0 = *(const float4*)(fptr + k0 + 32);
            fb1 = *(const float4*)(fptr + k0 + 36);
        }
        #pragma unroll
        for (int mt = 0; mt < 16; ++mt) {
            const short8 afrag = *(const short8*)(aptr + (size_t)(mt * 16) * DIM + k0);
            acc[mt] = __builtin_amdgcn_mfma_f32_16x16x32_bf16(afrag, bfrag, acc[mt], 0, 0, 0);
        }
    }

    // ---- epilogue: bias, per-head dots, softmax weight, ReLU, LayerNorm ----
    float qp[4] = {0.f, 0.f, 0.f, 0.f}, kp[4] = {0.f, 0.f, 0.f, 0.f};
    #pragma unroll
    for (int mt = 0; mt < 16; ++mt) {
        const int cbase = mt * 16 + quad * 4;
        const float4 bb = *(const float4*)(br + cbase);
        acc[mt][0] += bb.x; acc[mt][1] += bb.y; acc[mt][2] += bb.z; acc[mt][3] += bb.w;
        const float4 rq = *(const float4*)(rel_q + cbase);
        const float4 rk = *(const float4*)(rel_k + cbase);
        const int h = mt >> 2;
        qp[h] += acc[mt][0] * rq.x + acc[mt][1] * rq.y + acc[mt][2] * rq.z + acc[mt][3] * rq.w;
        kp[h] += acc[mt][0] * rk.x + acc[mt][1] * rk.y + acc[mt][2] * rk.z + acc[mt][3] * rk.w;
    }
    #pragma unroll
    for (int h = 0; h < 4; ++h) {
        qp[h] += __shfl_xor(qp[h], 16); qp[h] += __shfl_xor(qp[h], 32);
        kp[h] += __shfl_xor(kp[h], 16); kp[h] += __shfl_xor(kp[h], 32);
    }

    const int cnt = (int)mask[node] + (int)mask[N_NODES + node] + (int)mask[2 * N_NODES + node];

    float wgt[4];
    #pragma unroll
    for (int h = 0; h < 4; ++h) {
        const float q = qp[h];
        const float qk = q + kp[h];
        const float a = q  > 0.f ? q  : NEG * q;    // inactive-relation logit
        const float b = qk > 0.f ? qk : NEG * qk;   // active/self logit
        const float mx = fmaxf(a, b);
        const float eb = (float)(cnt + 1) * __expf(b - mx);
        const float ea = (float)(3 - cnt) * __expf(a - mx);
        wgt[h] = eb / (eb + ea);
    }

    float sum = 0.f, ssq = 0.f;
    #pragma unroll
    for (int mt = 0; mt < 16; ++mt) {
        const float w = wgt[mt >> 2];
        #pragma unroll
        for (int r = 0; r < 4; ++r) {
            float v = fmaxf(acc[mt][r] * w, 0.f);   // ReLU
            acc[mt][r] = v;
            sum += v; ssq += v * v;
        }
    }
    sum += __shfl_xor(sum, 16); sum += __shfl_xor(sum, 32);
    ssq += __shfl_xor(ssq, 16); ssq += __shfl_xor(ssq, 32);
    const float mu = sum * (1.f / 256.f);
    const float var = ssq * (1.f / 256.f) - mu * mu;
    const float rstd = rsqrtf(var + LN_EPS);

    if (valid) {
        float* optr = out + (size_t)node * DIM;
        #pragma unroll
        for (int mt = 0; mt < 16; ++mt) {
            const int cbase = mt * 16 + quad * 4;
            const float4 g = *(const float4*)(gamma + cbase);
            const float4 b = *(const float4*)(beta_p + cbase);
            float4 r;
            r.x = (acc[mt][0] - mu) * rstd * g.x + b.x;
            r.y = (acc[mt][1] - mu) * rstd * g.y + b.y;
            r.z = (acc[mt][2] - mu) * rstd * g.z + b.z;
            r.w = (acc[mt][3] - mu) * rstd * g.w + b.w;
            *(float4*)(optr + cbase) = r;
        }
    }
}

extern "C" void kernel_launch(void* const* d_in, const int* in_sizes, int n_in,
                              void* d_out, int out_size, void* d_ws, size_t ws_size,
                              hipStream_t stream) {
    const float* feat  = (const float*)d_in[0];
    // d_in[1] Wl, d_in[2] bl, d_in[5] attn_l, d_in[6] attn_r, edge_src_*: dead code
    const float* Wr    = (const float*)d_in[3];
    const float* br    = (const float*)d_in[4];
    const float* rel_q = (const float*)d_in[7];
    const float* rel_k = (const float*)d_in[8];
    const float* gamma = (const float*)d_in[9];
    const float* beta  = (const float*)d_in[10];
    const int* dst0 = (const int*)d_in[12];
    const int* dst1 = (const int*)d_in[14];
    const int* dst2 = (const int*)d_in[16];
    const int E = in_sizes[12];

    // d_ws layout: WrT (131072 B) | priv bitmaps (8 x 18752 B) | byte mask (150016 B)
    unsigned short* WrT = (unsigned short*)d_ws;
    unsigned int* priv  = (unsigned int*)((char*)d_ws + DIM * DIM * 2);
    unsigned char* mask = (unsigned char*)(priv + (size_t)SC_BLOCKS * BM_WORDS);

    wr_to_bf16T<<<16, 256, 0, stream>>>(Wr, WrT);
    scatter_priv<<<SC_BLOCKS, 256, 0, stream>>>(dst0, dst1, dst2, E, priv);
    merge_bm<<<(BM_WORDS + 255) / 256, 256, 0, stream>>>(priv, mask);
    fused_mfma<<<(N_NODES + 63) / 64, 256, 0, stream>>>(
        feat, WrT, br, rel_q, rel_k, gamma, beta, mask, (float*)d_out);
}

// Round 6
// 211.567 us; speedup vs baseline: 1.8840x; 1.8840x over previous
//
#include <hip/hip_runtime.h>

#define N_NODES 50000
#define DIM 256
#define NEG 0.2f
#define LN_EPS 1e-5f
#define BM_WORDS 4688           // ceil(3*50000/32) bitmap words
#define SC_BLOCKS 64

typedef __attribute__((ext_vector_type(8))) short short8;   // 8 x bf16 (4 VGPRs)
typedef __attribute__((ext_vector_type(4))) float f32x4;    // MFMA accumulator

__device__ __forceinline__ unsigned short f2bf(float x) {   // RNE fp32 -> bf16
    unsigned int u = __builtin_bit_cast(unsigned int, x);
    u += 0x7fffu + ((u >> 16) & 1u);
    return (unsigned short)(u >> 16);
}

// ---------- Wr (256x256 fp32) -> WrT bf16 [m][k] ----------
__global__ __launch_bounds__(256) void wr_to_bf16T(const float* __restrict__ Wr,
                                                   unsigned short* __restrict__ WrT) {
    __shared__ float tile[64][65];
    const int bx = (blockIdx.x & 3) * 64;    // k block
    const int by = (blockIdx.x >> 2) * 64;   // m block
    const int c = threadIdx.x & 63;
    const int r0 = threadIdx.x >> 6;
    #pragma unroll
    for (int i = 0; i < 16; ++i) {
        int r = r0 * 16 + i;
        tile[r][c] = Wr[(size_t)(bx + r) * DIM + by + c];   // coalesced read
    }
    __syncthreads();
    #pragma unroll
    for (int i = 0; i < 16; ++i) {
        int r = r0 * 16 + i;
        WrT[(size_t)(by + r) * DIM + bx + c] = f2bf(tile[c][r]);  // coalesced write
    }
}

// ---------- per-block private bitmaps: LDS atomics only, plain full-slice stores ----------
__global__ __launch_bounds__(1024) void scatter_priv(
    const int* __restrict__ d0, const int* __restrict__ d1, const int* __restrict__ d2,
    int E, unsigned int* __restrict__ priv)
{
    __shared__ unsigned int lbm[BM_WORDS];
    for (int i = threadIdx.x; i < BM_WORDS; i += 1024) lbm[i] = 0u;
    __syncthreads();

    const int total = 3 * E;
    const int per = (total + SC_BLOCKS - 1) / SC_BLOCKS;
    const int start = blockIdx.x * per;
    const int end = min(start + per, total);
    for (int i = start + (int)threadIdx.x; i < end; i += 1024) {
        const int* d; int base, e;
        if (i >= 2 * E)  { d = d2; e = i - 2 * E; base = 2 * N_NODES; }
        else if (i >= E) { d = d1; e = i - E;     base = N_NODES; }
        else             { d = d0; e = i;         base = 0; }
        const int bit = base + d[e];
        atomicOr(&lbm[bit >> 5], 1u << (bit & 31));   // workgroup-scope LDS atomic
    }
    __syncthreads();

    unsigned int* dst = priv + (size_t)blockIdx.x * BM_WORDS;
    for (int i = threadIdx.x; i < BM_WORDS; i += 1024) dst[i] = lbm[i];  // plain, every word
}

// ---------- merge 64 private maps -> byte mask (plain loads/stores, covers every byte) ----------
__global__ __launch_bounds__(256) void merge_bm(const unsigned int* __restrict__ priv,
                                                unsigned char* __restrict__ mask) {
    const int i = blockIdx.x * 256 + threadIdx.x;   // bitmap word index
    if (i >= BM_WORDS) return;
    unsigned int v = 0u;
    #pragma unroll
    for (int b = 0; b < SC_BLOCKS; ++b) v |= priv[(size_t)b * BM_WORDS + i];
    unsigned int* mw = (unsigned int*)(mask + (size_t)i * 32);   // 32-byte aligned
    #pragma unroll
    for (int j = 0; j < 8; ++j) {
        const unsigned int n = v >> (4 * j);
        mw[j] = (n & 1u) | ((n >> 1) & 1u) << 8 | ((n >> 2) & 1u) << 16 | ((n >> 3) & 1u) << 24;
    }
}

// ---------- fused MFMA GEMM + analytic-collapse epilogue ----------
// Round-2 structure (wave-independent, no LDS, no barriers) + register double-buffer
// of A-frags/feat across k-steps. FP order identical to the validated round-2 kernel.
__global__ __launch_bounds__(256, 2) void fused_mfma(
    const float* __restrict__ feat, const unsigned short* __restrict__ WrT,
    const float* __restrict__ br, const float* __restrict__ rel_q,
    const float* __restrict__ rel_k, const float* __restrict__ gamma,
    const float* __restrict__ beta_p, const unsigned char* __restrict__ mask,
    float* __restrict__ out)
{
    const int lane = threadIdx.x & 63;
    const int wave = threadIdx.x >> 6;
    const int ln = lane & 15;      // node within wave / MFMA n
    const int quad = lane >> 4;    // MFMA k-quad & D-row-quad
    int node = blockIdx.x * 64 + wave * 16 + ln;
    const bool valid = node < N_NODES;
    if (!valid) node = N_NODES - 1;              // clamp: loads safe, store guarded

    f32x4 acc[16];
    #pragma unroll
    for (int mt = 0; mt < 16; ++mt) acc[mt] = (f32x4){0.f, 0.f, 0.f, 0.f};

    const float* fptr = feat + (size_t)node * DIM + quad * 8;
    const unsigned short* aptr = WrT + (size_t)ln * DIM + quad * 8;

    short8 A[2][16];
    float4 F[2][2];

    #pragma unroll
    for (int mt = 0; mt < 16; ++mt) A[0][mt] = *(const short8*)(aptr + (size_t)(mt * 16) * DIM);
    F[0][0] = *(const float4*)(fptr);
    F[0][1] = *(const float4*)(fptr + 4);

    #pragma unroll
    for (int kk = 0; kk < 8; ++kk) {
        const int cur = kk & 1, nxt = cur ^ 1;
        if (kk < 7) {                            // batch-issue next k-step's loads
            const int k0 = (kk + 1) * 32;
            #pragma unroll
            for (int mt = 0; mt < 16; ++mt)
                A[nxt][mt] = *(const short8*)(aptr + (size_t)(mt * 16) * DIM + k0);
            F[nxt][0] = *(const float4*)(fptr + k0);
            F[nxt][1] = *(const float4*)(fptr + k0 + 4);
        }
        short8 bfrag;
        {
            const float4 a4 = F[cur][0], b4 = F[cur][1];
            bfrag[0] = (short)f2bf(a4.x); bfrag[1] = (short)f2bf(a4.y);
            bfrag[2] = (short)f2bf(a4.z); bfrag[3] = (short)f2bf(a4.w);
            bfrag[4] = (short)f2bf(b4.x); bfrag[5] = (short)f2bf(b4.y);
            bfrag[6] = (short)f2bf(b4.z); bfrag[7] = (short)f2bf(b4.w);
        }
        #pragma unroll
        for (int mt = 0; mt < 16; ++mt)
            acc[mt] = __builtin_amdgcn_mfma_f32_16x16x32_bf16(A[cur][mt], bfrag, acc[mt], 0, 0, 0);
    }

    // ---- epilogue: bias, per-head dots, softmax weight, ReLU, LayerNorm ----
    float qp[4] = {0.f, 0.f, 0.f, 0.f}, kp[4] = {0.f, 0.f, 0.f, 0.f};
    #pragma unroll
    for (int mt = 0; mt < 16; ++mt) {
        const int cbase = mt * 16 + quad * 4;
        const float4 bb = *(const float4*)(br + cbase);
        acc[mt][0] += bb.x; acc[mt][1] += bb.y; acc[mt][2] += bb.z; acc[mt][3] += bb.w;
        const float4 rq = *(const float4*)(rel_q + cbase);
        const float4 rk = *(const float4*)(rel_k + cbase);
        const int h = mt >> 2;
        qp[h] += acc[mt][0] * rq.x + acc[mt][1] * rq.y + acc[mt][2] * rq.z + acc[mt][3] * rq.w;
        kp[h] += acc[mt][0] * rk.x + acc[mt][1] * rk.y + acc[mt][2] * rk.z + acc[mt][3] * rk.w;
    }
    #pragma unroll
    for (int h = 0; h < 4; ++h) {
        qp[h] += __shfl_xor(qp[h], 16); qp[h] += __shfl_xor(qp[h], 32);
        kp[h] += __shfl_xor(kp[h], 16); kp[h] += __shfl_xor(kp[h], 32);
    }

    const int cnt = (int)mask[node] + (int)mask[N_NODES + node] + (int)mask[2 * N_NODES + node];

    float wgt[4];
    #pragma unroll
    for (int h = 0; h < 4; ++h) {
        const float q = qp[h];
        const float qk = q + kp[h];
        const float a = q  > 0.f ? q  : NEG * q;    // inactive-relation logit
        const float b = qk > 0.f ? qk : NEG * qk;   // active/self logit
        const float mx = fmaxf(a, b);
        const float eb = (float)(cnt + 1) * __expf(b - mx);
        const float ea = (float)(3 - cnt) * __expf(a - mx);
        wgt[h] = eb / (eb + ea);
    }

    float sum = 0.f, ssq = 0.f;
    #pragma unroll
    for (int mt = 0; mt < 16; ++mt) {
        const float w = wgt[mt >> 2];
        #pragma unroll
        for (int r = 0; r < 4; ++r) {
            float v = fmaxf(acc[mt][r] * w, 0.f);   // ReLU
            acc[mt][r] = v;
            sum += v; ssq += v * v;
        }
    }
    sum += __shfl_xor(sum, 16); sum += __shfl_xor(sum, 32);
    ssq += __shfl_xor(ssq, 16); ssq += __shfl_xor(ssq, 32);
    const float mu = sum * (1.f / 256.f);
    const float var = ssq * (1.f / 256.f) - mu * mu;
    const float rstd = rsqrtf(var + LN_EPS);

    if (valid) {
        float* optr = out + (size_t)node * DIM;
        #pragma unroll
        for (int mt = 0; mt < 16; ++mt) {
            const int cbase = mt * 16 + quad * 4;
            const float4 g = *(const float4*)(gamma + cbase);
            const float4 b = *(const float4*)(beta_p + cbase);
            float4 r;
            r.x = (acc[mt][0] - mu) * rstd * g.x + b.x;
            r.y = (acc[mt][1] - mu) * rstd * g.y + b.y;
            r.z = (acc[mt][2] - mu) * rstd * g.z + b.z;
            r.w = (acc[mt][3] - mu) * rstd * g.w + b.w;
            *(float4*)(optr + cbase) = r;
        }
    }
}

extern "C" void kernel_launch(void* const* d_in, const int* in_sizes, int n_in,
                              void* d_out, int out_size, void* d_ws, size_t ws_size,
                              hipStream_t stream) {
    const float* feat  = (const float*)d_in[0];
    // d_in[1] Wl, d_in[2] bl, d_in[5] attn_l, d_in[6] attn_r, edge_src_*: dead code
    const float* Wr    = (const float*)d_in[3];
    const float* br    = (const float*)d_in[4];
    const float* rel_q = (const float*)d_in[7];
    const float* rel_k = (const float*)d_in[8];
    const float* gamma = (const float*)d_in[9];
    const float* beta  = (const float*)d_in[10];
    const int* dst0 = (const int*)d_in[12];
    const int* dst1 = (const int*)d_in[14];
    const int* dst2 = (const int*)d_in[16];
    const int E = in_sizes[12];

    // d_ws layout: WrT (131072 B) | priv bitmaps (64 x 18752 B) | byte mask (150016 B)
    unsigned short* WrT = (unsigned short*)d_ws;
    unsigned int* priv  = (unsigned int*)((char*)d_ws + DIM * DIM * 2);
    unsigned char* mask = (unsigned char*)(priv + (size_t)SC_BLOCKS * BM_WORDS);

    wr_to_bf16T<<<16, 256, 0, stream>>>(Wr, WrT);
    scatter_priv<<<SC_BLOCKS, 1024, 0, stream>>>(dst0, dst1, dst2, E, priv);
    merge_bm<<<(BM_WORDS + 255) / 256, 256, 0, stream>>>(priv, mask);
    fused_mfma<<<(N_NODES + 63) / 64, 256, 0, stream>>>(
        feat, WrT, br, rel_q, rel_k, gamma, beta, mask, (float*)d_out);
}

// Round 9
// 208.791 us; speedup vs baseline: 1.9090x; 1.0133x over previous
//
#include <hip/hip_runtime.h>

#define N_NODES 50000
#define DIM 256
#define NEG 0.2f
#define LN_EPS 1e-5f
#define BM_WORDS 4688           // ceil(3*50000/32) bitmap words
#define SC_BLOCKS 64

typedef __attribute__((ext_vector_type(8))) short short8;   // 8 x bf16 (4 VGPRs)
typedef __attribute__((ext_vector_type(4))) float f32x4;    // MFMA accumulator

__device__ __forceinline__ unsigned short f2bf(float x) {   // RNE fp32 -> bf16
    unsigned int u = __builtin_bit_cast(unsigned int, x);
    u += 0x7fffu + ((u >> 16) & 1u);
    return (unsigned short)(u >> 16);
}

// ---------- Wr (256x256 fp32) -> WrT bf16 [m][k]  (verbatim r6, proven) ----------
__global__ __launch_bounds__(256) void wr_to_bf16T(const float* __restrict__ Wr,
                                                   unsigned short* __restrict__ WrT) {
    __shared__ float tile[64][65];
    const int bx = (blockIdx.x & 3) * 64;    // k block
    const int by = (blockIdx.x >> 2) * 64;   // m block
    const int c = threadIdx.x & 63;
    const int r0 = threadIdx.x >> 6;
    #pragma unroll
    for (int i = 0; i < 16; ++i) {
        int r = r0 * 16 + i;
        tile[r][c] = Wr[(size_t)(bx + r) * DIM + by + c];   // coalesced read
    }
    __syncthreads();
    #pragma unroll
    for (int i = 0; i < 16; ++i) {
        int r = r0 * 16 + i;
        WrT[(size_t)(by + r) * DIM + bx + c] = f2bf(tile[c][r]);  // coalesced write
    }
}

// ---------- per-block private bitmaps (r6 structure; inner loop 8-way batched) ----------
// Same atomics in a different order: OR is order-independent -> bit-identical result.
__global__ __launch_bounds__(1024) void scatter_priv(
    const int* __restrict__ d0, const int* __restrict__ d1, const int* __restrict__ d2,
    int E, unsigned int* __restrict__ priv)
{
    __shared__ unsigned int lbm[BM_WORDS];
    for (int i = threadIdx.x; i < BM_WORDS; i += 1024) lbm[i] = 0u;
    __syncthreads();

    const int total = 3 * E;
    const int per = (total + SC_BLOCKS - 1) / SC_BLOCKS;
    const int start = blockIdx.x * per;
    const int end = min(start + per, total);

    int i = start + (int)threadIdx.x;
    // batched phase: issue 8 independent loads, then 8 LDS atomics
    for (; i + 7 * 1024 < end; i += 8 * 1024) {
        int bit[8];
        #pragma unroll
        for (int u = 0; u < 8; ++u) {
            const int idx = i + u * 1024;
            const int* d; int base, e;
            if (idx >= 2 * E)  { d = d2; e = idx - 2 * E; base = 2 * N_NODES; }
            else if (idx >= E) { d = d1; e = idx - E;     base = N_NODES; }
            else               { d = d0; e = idx;         base = 0; }
            bit[u] = base + d[e];                   // loads batch: no inter-dependence
        }
        #pragma unroll
        for (int u = 0; u < 8; ++u)
            atomicOr(&lbm[bit[u] >> 5], 1u << (bit[u] & 31));
    }
    for (; i < end; i += 1024) {                    // tail
        const int* d; int base, e;
        if (i >= 2 * E)  { d = d2; e = i - 2 * E; base = 2 * N_NODES; }
        else if (i >= E) { d = d1; e = i - E;     base = N_NODES; }
        else             { d = d0; e = i;         base = 0; }
        const int bit = base + d[e];
        atomicOr(&lbm[bit >> 5], 1u << (bit & 31));
    }
    __syncthreads();

    unsigned int* dst = priv + (size_t)blockIdx.x * BM_WORDS;
    for (int j = threadIdx.x; j < BM_WORDS; j += 1024) dst[j] = lbm[j];  // plain, every word
}

// ---------- merge 64 private maps -> byte mask (verbatim r6, proven pass) ----------
__global__ __launch_bounds__(256) void merge_bm(const unsigned int* __restrict__ priv,
                                                unsigned char* __restrict__ mask) {
    const int i = blockIdx.x * 256 + threadIdx.x;   // bitmap word index
    if (i >= BM_WORDS) return;
    unsigned int v = 0u;
    #pragma unroll
    for (int b = 0; b < SC_BLOCKS; ++b) v |= priv[(size_t)b * BM_WORDS + i];
    unsigned int* mw = (unsigned int*)(mask + (size_t)i * 32);   // 32-byte aligned
    #pragma unroll
    for (int j = 0; j < 8; ++j) {
        const unsigned int n = v >> (4 * j);
        mw[j] = (n & 1u) | ((n >> 1) & 1u) << 8 | ((n >> 2) & 1u) << 16 | ((n >> 3) & 1u) << 24;
    }
}

// ---------- fused MFMA GEMM + analytic-collapse epilogue (VERBATIM r6, proven pass) ----------
// Each wave: 16 nodes (lane&15) x 256 out-cols (16 m-tiles). No LDS, no barriers.
__global__ __launch_bounds__(256, 2) void fused_mfma(
    const float* __restrict__ feat, const unsigned short* __restrict__ WrT,
    const float* __restrict__ br, const float* __restrict__ rel_q,
    const float* __restrict__ rel_k, const float* __restrict__ gamma,
    const float* __restrict__ beta_p, const unsigned char* __restrict__ mask,
    float* __restrict__ out)
{
    const int lane = threadIdx.x & 63;
    const int wave = threadIdx.x >> 6;
    const int ln = lane & 15;      // node within wave / MFMA n
    const int quad = lane >> 4;    // MFMA k-quad & D-row-quad
    int node = blockIdx.x * 64 + wave * 16 + ln;
    const bool valid = node < N_NODES;
    if (!valid) node = N_NODES - 1;              // clamp: loads safe, store guarded

    f32x4 acc[16];
    #pragma unroll
    for (int mt = 0; mt < 16; ++mt) acc[mt] = (f32x4){0.f, 0.f, 0.f, 0.f};

    const float* fptr = feat + (size_t)node * DIM + quad * 8;
    const unsigned short* aptr = WrT + (size_t)ln * DIM + quad * 8;

    short8 A[2][16];
    float4 F[2][2];

    #pragma unroll
    for (int mt = 0; mt < 16; ++mt) A[0][mt] = *(const short8*)(aptr + (size_t)(mt * 16) * DIM);
    F[0][0] = *(const float4*)(fptr);
    F[0][1] = *(const float4*)(fptr + 4);

    #pragma unroll
    for (int kk = 0; kk < 8; ++kk) {
        const int cur = kk & 1, nxt = cur ^ 1;
        if (kk < 7) {                            // batch-issue next k-step's loads
            const int k0 = (kk + 1) * 32;
            #pragma unroll
            for (int mt = 0; mt < 16; ++mt)
                A[nxt][mt] = *(const short8*)(aptr + (size_t)(mt * 16) * DIM + k0);
            F[nxt][0] = *(const float4*)(fptr + k0);
            F[nxt][1] = *(const float4*)(fptr + k0 + 4);
        }
        short8 bfrag;
        {
            const float4 a4 = F[cur][0], b4 = F[cur][1];
            bfrag[0] = (short)f2bf(a4.x); bfrag[1] = (short)f2bf(a4.y);
            bfrag[2] = (short)f2bf(a4.z); bfrag[3] = (short)f2bf(a4.w);
            bfrag[4] = (short)f2bf(b4.x); bfrag[5] = (short)f2bf(b4.y);
            bfrag[6] = (short)f2bf(b4.z); bfrag[7] = (short)f2bf(b4.w);
        }
        #pragma unroll
        for (int mt = 0; mt < 16; ++mt)
            acc[mt] = __builtin_amdgcn_mfma_f32_16x16x32_bf16(A[cur][mt], bfrag, acc[mt], 0, 0, 0);
    }

    // ---- epilogue: bias, per-head dots, softmax weight, ReLU, LayerNorm ----
    float qp[4] = {0.f, 0.f, 0.f, 0.f}, kp[4] = {0.f, 0.f, 0.f, 0.f};
    #pragma unroll
    for (int mt = 0; mt < 16; ++mt) {
        const int cbase = mt * 16 + quad * 4;
        const float4 bb = *(const float4*)(br + cbase);
        acc[mt][0] += bb.x; acc[mt][1] += bb.y; acc[mt][2] += bb.z; acc[mt][3] += bb.w;
        const float4 rq = *(const float4*)(rel_q + cbase);
        const float4 rk = *(const float4*)(rel_k + cbase);
        const int h = mt >> 2;
        qp[h] += acc[mt][0] * rq.x + acc[mt][1] * rq.y + acc[mt][2] * rq.z + acc[mt][3] * rq.w;
        kp[h] += acc[mt][0] * rk.x + acc[mt][1] * rk.y + acc[mt][2] * rk.z + acc[mt][3] * rk.w;
    }
    #pragma unroll
    for (int h = 0; h < 4; ++h) {
        qp[h] += __shfl_xor(qp[h], 16); qp[h] += __shfl_xor(qp[h], 32);
        kp[h] += __shfl_xor(kp[h], 16); kp[h] += __shfl_xor(kp[h], 32);
    }

    const int cnt = (int)mask[node] + (int)mask[N_NODES + node] + (int)mask[2 * N_NODES + node];

    float wgt[4];
    #pragma unroll
    for (int h = 0; h < 4; ++h) {
        const float q = qp[h];
        const float qk = q + kp[h];
        const float a = q  > 0.f ? q  : NEG * q;    // inactive-relation logit
        const float b = qk > 0.f ? qk : NEG * qk;   // active/self logit
        const float mx = fmaxf(a, b);
        const float eb = (float)(cnt + 1) * __expf(b - mx);
        const float ea = (float)(3 - cnt) * __expf(a - mx);
        wgt[h] = eb / (eb + ea);
    }

    float sum = 0.f, ssq = 0.f;
    #pragma unroll
    for (int mt = 0; mt < 16; ++mt) {
        const float w = wgt[mt >> 2];
        #pragma unroll
        for (int r = 0; r < 4; ++r) {
            float v = fmaxf(acc[mt][r] * w, 0.f);   // ReLU
            acc[mt][r] = v;
            sum += v; ssq += v * v;
        }
    }
    sum += __shfl_xor(sum, 16); sum += __shfl_xor(sum, 32);
    ssq += __shfl_xor(ssq, 16); ssq += __shfl_xor(ssq, 32);
    const float mu = sum * (1.f / 256.f);
    const float var = ssq * (1.f / 256.f) - mu * mu;
    const float rstd = rsqrtf(var + LN_EPS);

    if (valid) {
        float* optr = out + (size_t)node * DIM;
        #pragma unroll
        for (int mt = 0; mt < 16; ++mt) {
            const int cbase = mt * 16 + quad * 4;
            const float4 g = *(const float4*)(gamma + cbase);
            const float4 b = *(const float4*)(beta_p + cbase);
            float4 r;
            r.x = (acc[mt][0] - mu) * rstd * g.x + b.x;
            r.y = (acc[mt][1] - mu) * rstd * g.y + b.y;
            r.z = (acc[mt][2] - mu) * rstd * g.z + b.z;
            r.w = (acc[mt][3] - mu) * rstd * g.w + b.w;
            *(float4*)(optr + cbase) = r;
        }
    }
}

extern "C" void kernel_launch(void* const* d_in, const int* in_sizes, int n_in,
                              void* d_out, int out_size, void* d_ws, size_t ws_size,
                              hipStream_t stream) {
    const float* feat  = (const float*)d_in[0];
    // d_in[1] Wl, d_in[2] bl, d_in[5] attn_l, d_in[6] attn_r, edge_src_*: dead code
    const float* Wr    = (const float*)d_in[3];
    const float* br    = (const float*)d_in[4];
    const float* rel_q = (const float*)d_in[7];
    const float* rel_k = (const float*)d_in[8];
    const float* gamma = (const float*)d_in[9];
    const float* beta  = (const float*)d_in[10];
    const int* dst0 = (const int*)d_in[12];
    const int* dst1 = (const int*)d_in[14];
    const int* dst2 = (const int*)d_in[16];
    const int E = in_sizes[12];

    // d_ws layout: WrT (131072 B) | priv bitmaps (64 x 18752 B) | byte mask (150016 B)
    unsigned short* WrT = (unsigned short*)d_ws;
    unsigned int* priv  = (unsigned int*)((char*)d_ws + DIM * DIM * 2);
    unsigned char* mask = (unsigned char*)(priv + (size_t)SC_BLOCKS * BM_WORDS);

    wr_to_bf16T<<<16, 256, 0, stream>>>(Wr, WrT);
    scatter_priv<<<SC_BLOCKS, 1024, 0, stream>>>(dst0, dst1, dst2, E, priv);
    merge_bm<<<(BM_WORDS + 255) / 256, 256, 0, stream>>>(priv, mask);
    fused_mfma<<<(N_NODES + 63) / 64, 256, 0, stream>>>(
        feat, WrT, br, rel_q, rel_k, gamma, beta, mask, (float*)d_out);
}